// Round 14
// baseline (208.933 us; speedup 1.0000x reference)
//
#include <hip/hip_runtime.h>

typedef unsigned short u16;
typedef unsigned int u32;
typedef __bf16 bf16x8 __attribute__((ext_vector_type(8)));
typedef float f32x2 __attribute__((ext_vector_type(2)));
typedef float f32x4 __attribute__((ext_vector_type(4)));
typedef float f32x16 __attribute__((ext_vector_type(16)));

#define S_LEN 2048
#define EMB 1024
#define NH 16
#define HD 64
#define LOG2E 1.44269504088896f
#define QSCALE (0.125f * LOG2E)
#define THRL 11.5415603f /* 8 * LOG2E */
#define FB(r) ((((r) ^ ((r) >> 2))) & 3)
#define MEMB asm volatile("" ::: "memory")

__device__ __forceinline__ u16 f2bf(float f) {
  union { float f; unsigned u; } v; v.f = f;
  unsigned r = (v.u + 0x7fffu + ((v.u >> 16) & 1u)) >> 16;
  return (u16)r;
}

__device__ __forceinline__ u32 packbf(float a, float b) {
  union { __bf16 h[2]; u32 u; } x;
  x.h[0] = (__bf16)a; x.h[1] = (__bf16)b;
  return x.u;
}

__device__ __forceinline__ void g2l16(const void* g, void* l) {
  __builtin_amdgcn_global_load_lds(
      (const unsigned int __attribute__((address_space(1)))*)g,
      (unsigned int __attribute__((address_space(3)))*)l, 16, 0, 0);
}

__device__ __forceinline__ float permswap_max(float a) {
  auto r = __builtin_amdgcn_permlane32_swap(__float_as_int(a), __float_as_int(a), false, false);
  return fmaxf(__int_as_float(r[0]), __int_as_float(r[1]));
}
__device__ __forceinline__ float permswap_add(float a) {
  auto r = __builtin_amdgcn_permlane32_swap(__float_as_int(a), __float_as_int(a), false, false);
  return __int_as_float(r[0]) + __int_as_float(r[1]);
}

__device__ __forceinline__ void phase_end() {
  asm volatile("s_waitcnt lgkmcnt(0)" ::: "memory");
  asm volatile("s_waitcnt vmcnt(0)" ::: "memory");
  __builtin_amdgcn_s_barrier();
  MEMB;
}

// ---------------- conversion kernels ----------------

__global__ void cvt_bf16_2(const float* __restrict__ aq, const float* __restrict__ akv,
                           u16* __restrict__ dq, u16* __restrict__ dkv) {
  int i = blockIdx.x * blockDim.x + threadIdx.x;
  const float4* s;
  ushort4* d;
  int j;
  if (i < 2097152) {
    s = (const float4*)aq; d = (ushort4*)dq; j = i;
  } else {
    s = (const float4*)akv; d = (ushort4*)dkv; j = i - 2097152;
  }
  float4 f = s[j];
  ushort4 o;
  o.x = f2bf(f.x); o.y = f2bf(f.y); o.z = f2bf(f.z); o.w = f2bf(f.w);
  d[j] = o;
}

__global__ void transcvt4(const float* __restrict__ W0, const float* __restrict__ W1,
                          const float* __restrict__ W2, const float* __restrict__ W3,
                          u16* __restrict__ Dqkv, u16* __restrict__ Do) {
  __shared__ float t[32][33];
  const int z = blockIdx.z;
  const float* W = (z == 0) ? W0 : (z == 1) ? W1 : (z == 2) ? W2 : W3;
  u16* Wt = (z < 3) ? (Dqkv + (size_t)z * 1048576) : Do;
  int k0 = blockIdx.x * 32, n0 = blockIdx.y * 32;
  int tx = threadIdx.x & 31, ty = threadIdx.x >> 5;
#pragma unroll
  for (int i = 0; i < 4; i++) t[ty + i * 8][tx] = W[(k0 + ty + i * 8) * 1024 + n0 + tx];
  __syncthreads();
#pragma unroll
  for (int i = 0; i < 4; i++) Wt[(n0 + ty + i * 8) * 1024 + k0 + tx] = f2bf(t[tx][ty + i * 8]);
}

// bias table in log2 units, 256 entries/head (bucket saturates at dist>=113)
__global__ void build_bias(const float* __restrict__ rel, float* __restrict__ tbl) {
  int i = blockIdx.x * 256 + threadIdx.x;  // 0..4095
  int h = i >> 8, dist = i & 255;
  int bk;
  if (dist < 16) {
    bk = dist;
  } else {
    float ls = logf((float)dist * (1.0f / 16.0f)) * (1.0f / logf(8.0f));
    bk = 16 + (int)(ls * 16.0f);
    if (bk > 31) bk = 31;
  }
  tbl[i] = rel[h * 32 + bk] * LOG2E;
}

// ---------------- fused QKV GEMM: 128x128, BK=32, 3-buffer counted-vmcnt ----------------
// SWAPPED MFMA (acc = C^T): reg-quad -> 4 consecutive n, lane -> m.

__global__ __launch_bounds__(256, 3) void gemm_qkv(const u16* __restrict__ Aq,
                                                   const u16* __restrict__ Akv,
                                                   const u16* __restrict__ Wt,
                                                   u16* __restrict__ QKV, float qscale) {
  constexpr int K = EMB;
  __shared__ u16 As[3][128 * 32];
  __shared__ u16 Bs[3][128 * 32];

  const int bid = blockIdx.x;
  const int xcd = bid & 7, idx = bid >> 3;  // 192 blocks per XCD chunk
  const int mt = xcd * 8 + (idx & 7);       // 64 m-tiles
  const int nt = idx >> 3;                  // 24 n-tiles
  const int m0 = mt * 128;
  const int n0 = nt * 128;
  const int mat = n0 >> 10;  // 0=Q 1=K 2=V (block-uniform)
  const u16* A = (mat == 0) ? Aq : Akv;

  const int tid = threadIdx.x;
  const int lane = tid & 63;
  const int wid = tid >> 6;
  const int wm = (wid >> 1) * 64;
  const int wn = (wid & 1) * 64;
  const int la = lane & 15;
  const int lg = lane >> 4;

  const int r0 = tid >> 2;
  const int c0 = ((tid & 3) ^ FB(r0)) * 8;
  const u16* gA = A + (size_t)(m0 + r0) * K + c0;
  const u16* gB = Wt + (size_t)(n0 + r0) * K + c0;

  auto stage = [&](int b) {
    u16* lA = As[b] + tid * 8;
    u16* lB = Bs[b] + tid * 8;
    g2l16(gA, lA);
    g2l16(gA + 64 * K, lA + 2048);
    g2l16(gB, lB);
    g2l16(gB + 64 * K, lB + 2048);
    gA += 32;
    gB += 32;
  };

  f32x4 acc[4][4] = {};

  stage(0);
  stage(1);
  asm volatile("s_waitcnt vmcnt(4)" ::: "memory");
  __builtin_amdgcn_s_barrier();
  MEMB;

  int cur = 0;
  for (int t = 0; t < 32; ++t) {
    if (t < 30) {
      int nxt = cur + 2;
      if (nxt > 2) nxt -= 3;
      stage(nxt);
    }

    bf16x8 af[4], bb[4];
#pragma unroll
    for (int mf = 0; mf < 4; mf++) {
      int row = wm + mf * 16 + la;
      af[mf] = *(const bf16x8*)&As[cur][row * 32 + ((lg ^ FB(row)) << 3)];
    }
#pragma unroll
    for (int nf = 0; nf < 4; nf++) {
      int row = wn + nf * 16 + la;
      bb[nf] = *(const bf16x8*)&Bs[cur][row * 32 + ((lg ^ FB(row)) << 3)];
    }
    __builtin_amdgcn_s_setprio(1);
#pragma unroll
    for (int mf = 0; mf < 4; mf++)
#pragma unroll
      for (int nf = 0; nf < 4; nf++)
        acc[mf][nf] =
            __builtin_amdgcn_mfma_f32_16x16x32_bf16(bb[nf], af[mf], acc[mf][nf], 0, 0, 0);
    __builtin_amdgcn_s_setprio(0);

    asm volatile("s_waitcnt lgkmcnt(0)" ::: "memory");
    if (t < 30) asm volatile("s_waitcnt vmcnt(4)" ::: "memory");
    else        asm volatile("s_waitcnt vmcnt(0)" ::: "memory");
    __builtin_amdgcn_s_barrier();
    MEMB;

    cur = (cur == 2) ? 0 : cur + 1;
  }

  const float sc = (mat == 0) ? qscale : 1.0f;
  const size_t base = (size_t)mat << 23;
  if (mat < 2) {
#pragma unroll
    for (int mf = 0; mf < 4; mf++) {
      const int m = m0 + wm + mf * 16 + la;
      const int b = m >> 11, s = m & 2047;
#pragma unroll
      for (int nf = 0; nf < 4; nf++) {
        const int n = n0 + wn + nf * 16 + lg * 4;
        const int hh = (n >> 6) & 15, d0 = n & 63;
        ushort4 ov;
        ov.x = f2bf(acc[mf][nf][0] * sc);
        ov.y = f2bf(acc[mf][nf][1] * sc);
        ov.z = f2bf(acc[mf][nf][2] * sc);
        ov.w = f2bf(acc[mf][nf][3] * sc);
        *(ushort4*)&QKV[base + (((size_t)(b * 16 + hh) * 2048 + s) << 6) + d0] = ov;
      }
    }
  } else {
#pragma unroll
    for (int mf = 0; mf < 4; mf++) {
      const int m = m0 + wm + mf * 16 + la;
      const int b = m >> 11, s = m & 2047;
#pragma unroll
      for (int nf = 0; nf < 4; nf++)
#pragma unroll
        for (int r = 0; r < 4; r++) {
          const int n = n0 + wn + nf * 16 + lg * 4 + r;
          const int hh = (n >> 6) & 15, d = n & 63;
          QKV[base + (((size_t)(b * 16 + hh) * 64 + d) << 11) + s] = f2bf(acc[mf][nf][r]);
        }
    }
  }
}

// ---------------- output GEMM: out[M,1024] f32 = Ob * Wot^T ----------------

__global__ __launch_bounds__(256, 3) void gemm_out(const u16* __restrict__ A,
                                                   const u16* __restrict__ Bt,
                                                   float* __restrict__ C) {
  constexpr int K = EMB;
  __shared__ u16 As[3][128 * 32];
  __shared__ u16 Bs[3][128 * 32];
  const int bid = blockIdx.x;
  const int xcd = bid & 7, idx = bid >> 3;
  const int mt = xcd * 8 + (idx & 7);
  const int nt = idx >> 3;
  const int m0 = mt * 128;
  const int n0 = nt * 128;
  const int tid = threadIdx.x;
  const int lane = tid & 63;
  const int wid = tid >> 6;
  const int wm = (wid >> 1) * 64;
  const int wn = (wid & 1) * 64;
  const int la = lane & 15;
  const int lg = lane >> 4;

  const int r0 = tid >> 2;
  const int c0 = ((tid & 3) ^ FB(r0)) * 8;
  const u16* gA = A + (size_t)(m0 + r0) * K + c0;
  const u16* gB = Bt + (size_t)(n0 + r0) * K + c0;

  auto stage = [&](int b) {
    u16* lA = As[b] + tid * 8;
    u16* lB = Bs[b] + tid * 8;
    g2l16(gA, lA);
    g2l16(gA + 64 * K, lA + 2048);
    g2l16(gB, lB);
    g2l16(gB + 64 * K, lB + 2048);
    gA += 32;
    gB += 32;
  };

  f32x4 acc[4][4] = {};

  stage(0);
  stage(1);
  asm volatile("s_waitcnt vmcnt(4)" ::: "memory");
  __builtin_amdgcn_s_barrier();
  MEMB;

  int cur = 0;
  for (int t = 0; t < 32; ++t) {
    if (t < 30) {
      int nxt = cur + 2;
      if (nxt > 2) nxt -= 3;
      stage(nxt);
    }

    bf16x8 af[4], bb[4];
#pragma unroll
    for (int mf = 0; mf < 4; mf++) {
      int row = wm + mf * 16 + la;
      af[mf] = *(const bf16x8*)&As[cur][row * 32 + ((lg ^ FB(row)) << 3)];
    }
#pragma unroll
    for (int nf = 0; nf < 4; nf++) {
      int row = wn + nf * 16 + la;
      bb[nf] = *(const bf16x8*)&Bs[cur][row * 32 + ((lg ^ FB(row)) << 3)];
    }
    __builtin_amdgcn_s_setprio(1);
#pragma unroll
    for (int mf = 0; mf < 4; mf++)
#pragma unroll
      for (int nf = 0; nf < 4; nf++)
        acc[mf][nf] =
            __builtin_amdgcn_mfma_f32_16x16x32_bf16(bb[nf], af[mf], acc[mf][nf], 0, 0, 0);
    __builtin_amdgcn_s_setprio(0);

    asm volatile("s_waitcnt lgkmcnt(0)" ::: "memory");
    if (t < 30) asm volatile("s_waitcnt vmcnt(4)" ::: "memory");
    else        asm volatile("s_waitcnt vmcnt(0)" ::: "memory");
    __builtin_amdgcn_s_barrier();
    MEMB;

    cur = (cur == 2) ? 0 : cur + 1;
  }

#pragma unroll
  for (int mf = 0; mf < 4; mf++) {
    const int m = m0 + wm + mf * 16 + la;
#pragma unroll
    for (int nf = 0; nf < 4; nf++) {
      const int n = n0 + wn + nf * 16 + lg * 4;
      float4 ov;
      ov.x = acc[mf][nf][0];
      ov.y = acc[mf][nf][1];
      ov.z = acc[mf][nf][2];
      ov.w = acc[mf][nf][3];
      *(float4*)&C[(size_t)m * 1024 + n] = ov;
    }
  }
}

// ---------------- flash attention, 2-phase dbuf, full-residency grid ----------------
// grid (64 bh, 16 qt); 1024 blocks = 256 CU x 4 blocks/CU co-resident (LDS 33 KB).

__device__ __forceinline__ void softmax_repack(const f32x16* sacc, int kv0, int qw, int q, int hi,
                                               const float* bias_s, float bias31, float& mrun,
                                               float& lrun, f32x16& o0, f32x16& o1,
                                               u32 (&paw)[4][4]) {
  f32x2 pf[16];  // pf[j] = scores (r=2j', 2j'+1) of nf=j>>3, j'=j&7  (log2 units)
  float adde = 0.f;
  if (kv0 + 176 <= qw) {  // FAR: bucket 31 everywhere, bias folded into exp constant
#pragma unroll
    for (int j = 0; j < 16; j++) {
      const int nf = j >> 3, r = (j & 7) * 2;
      pf[j] = (f32x2){sacc[nf][r], sacc[nf][r + 1]};
    }
    adde = bias31;
  } else {
    const int qb2 = q - kv0 - 4 * hi;
    const float* bp = bias_s + (qb2 - 59);  // bp[59-Cn] = bias_s[qb2-Cn], Cn<=59
    if (kv0 + 63 <= qw) {  // NEAR-full: per-score bias, no mask
#pragma unroll
      for (int j = 0; j < 16; j++) {
        const int nf = j >> 3, r = (j & 7) * 2;
        const int Cn = nf * 32 + (r & 3) + ((r >> 2) << 3);
        f32x2 bv = {bp[59 - Cn], bp[58 - Cn]};
        pf[j] = (f32x2){sacc[nf][r], sacc[nf][r + 1]} + bv;
      }
    } else {  // DIAG: mask (OOB-LDS bias reads are masked out)
#pragma unroll
      for (int j = 0; j < 16; j++) {
        const int nf = j >> 3, r = (j & 7) * 2;
        const int Cn = nf * 32 + (r & 3) + ((r >> 2) << 3);
        pf[j].x = (Cn <= qb2) ? (sacc[nf][r] + bp[59 - Cn]) : -1e30f;
        pf[j].y = (Cn + 1 <= qb2) ? (sacc[nf][r + 1] + bp[58 - Cn]) : -1e30f;
      }
    }
  }

  // tile max: pk_max tree
  f32x2 t8[8];
#pragma unroll
  for (int i = 0; i < 8; i++) t8[i] = __builtin_elementwise_max(pf[i], pf[i + 8]);
#pragma unroll
  for (int i = 0; i < 4; i++) t8[i] = __builtin_elementwise_max(t8[i], t8[i + 4]);
  f32x2 m2 = __builtin_elementwise_max(__builtin_elementwise_max(t8[0], t8[1]),
                                       __builtin_elementwise_max(t8[2], t8[3]));
  float mt = fmaxf(m2.x, m2.y) + adde;
  mt = permswap_max(mt);

  // defer-max (T13)
  if (__any(mt > mrun + THRL)) {
    float mn = fmaxf(mrun, mt);
    float s = exp2f(mrun - mn);
    mrun = mn;
    lrun *= s;
    o0 *= s;
    o1 *= s;
  }
  const f32x2 ec2 = {adde - mrun, adde - mrun};

  // exp + sum
  f32x2 s8[8];
#pragma unroll
  for (int j = 0; j < 16; j++) {
    f32x2 a = pf[j] + ec2;
    f32x2 p = {exp2f(a.x), exp2f(a.y)};
    pf[j] = p;
    if (j < 8) s8[j] = p;
    else s8[j - 8] += p;
  }
#pragma unroll
  for (int i = 0; i < 4; i++) s8[i] += s8[i + 4];
  f32x2 s2 = (s8[0] + s8[1]) + (s8[2] + s8[3]);
  lrun += permswap_add(s2.x + s2.y);

  // repack P^T into PV B-fragments (pair-pack + permlane32_swap)
#pragma unroll
  for (int ks = 0; ks < 4; ks++) {
    const int j0b = (ks >> 1) * 8 + (ks & 1) * 4;
#pragma unroll
    for (int half = 0; half < 2; half++) {
      u32 Y0 = packbf(pf[j0b + half].x, pf[j0b + half].y);
      u32 Y1 = packbf(pf[j0b + 2 + half].x, pf[j0b + 2 + half].y);
      auto r = __builtin_amdgcn_permlane32_swap((int)Y0, (int)Y1, false, false);
      paw[ks][half] = (u32)r[0];
      paw[ks][2 + half] = (u32)r[1];
    }
  }
}

template <int CUR>
__device__ __forceinline__ void tile_body(int t, int ntblk, int qmax, int qw, int q, int hi,
                                          int la, int tid, const u16*& kp, const u16*& vp,
                                          u16 (*Ks)[64 * 64], u16 (*Vs)[64 * 64],
                                          const bf16x8 (&qfrag)[4], const float* bias_s,
                                          float bias31, float& mrun, float& lrun, f32x16& o0,
                                          f32x16& o1) {
  if (t + 1 < ntblk) {  // issue next-tile stage early; drains at end of this iter
    u16* lK = Ks[CUR ^ 1] + tid * 8;
    u16* lV = Vs[CUR ^ 1] + tid * 8;
    g2l16(kp, lK);
    g2l16(kp + 32 * 64, lK + 2048);
    g2l16(vp, lV);
    g2l16(vp + 32 * S_LEN, lV + 2048);
    kp += 4096;
    vp += 64;
  }

  const int kv0 = t << 6;
  if (kv0 <= qmax) {
    f32x16 sacc[2] = {};
    __builtin_amdgcn_s_setprio(1);
#pragma unroll
    for (int kk = 0; kk < 4; kk++)
#pragma unroll
      for (int nf = 0; nf < 2; nf++) {
        int row = nf * 32 + la;
        bf16x8 kf = *(const bf16x8*)&Ks[CUR][row * 64 + (((kk * 2 + hi) ^ (row & 7)) << 3)];
        sacc[nf] = __builtin_amdgcn_mfma_f32_32x32x16_bf16(kf, qfrag[kk], sacc[nf], 0, 0, 0);
      }
    __builtin_amdgcn_s_setprio(0);

    u32 paw[4][4];
    softmax_repack(sacc, kv0, qw, q, hi, bias_s, bias31, mrun, lrun, o0, o1, paw);

    __builtin_amdgcn_s_setprio(1);
#pragma unroll
    for (int d2 = 0; d2 < 2; d2++) {
      f32x16& oa = d2 ? o1 : o0;
#pragma unroll
      for (int ks = 0; ks < 4; ks++) {
        int row = d2 * 32 + la;
        bf16x8 vf = *(const bf16x8*)&Vs[CUR][row * 64 + (((ks * 2 + hi) ^ (row & 7)) << 3)];
        union { u32 w[4]; bf16x8 v; } pu;
        pu.w[0] = paw[ks][0]; pu.w[1] = paw[ks][1];
        pu.w[2] = paw[ks][2]; pu.w[3] = paw[ks][3];
        oa = __builtin_amdgcn_mfma_f32_32x32x16_bf16(vf, pu.v, oa, 0, 0, 0);
      }
    }
    __builtin_amdgcn_s_setprio(0);
  }

  phase_end();
}

__global__ __launch_bounds__(256, 4) void attn_kernel(const u16* __restrict__ Qb,
                                                      const u16* __restrict__ Kb,
                                                      const u16* __restrict__ Vtb,
                                                      const float* __restrict__ btbl,
                                                      u16* __restrict__ O) {
  __shared__ u16 Ks[2][64 * 64];
  __shared__ u16 Vs[2][64 * 64];
  __shared__ float bias_s[256];

  const int bh = blockIdx.x;
  const int h = bh & (NH - 1);
  const int b = bh >> 4;
  const int qt = 15 - blockIdx.y;  // heavy tiles dispatch first
  const int q0 = qt * 128;
  const int tid = threadIdx.x;
  const int lane = tid & 63;
  const int w = tid >> 6;
  const int la = lane & 31;
  const int hi = lane >> 5;

  if (tid < 64) ((float4*)bias_s)[tid] = ((const float4*)(btbl + h * 256))[tid];

  const u16* Qg = Qb + (size_t)bh * S_LEN * HD;
  const u16* Kg = Kb + (size_t)bh * S_LEN * HD;
  const u16* Vg = Vtb + (size_t)bh * HD * S_LEN;

  const int qw = q0 + w * 32;
  const int q = qw + la;

  bf16x8 qfrag[4];
#pragma unroll
  for (int kk = 0; kk < 4; kk++)
    qfrag[kk] = *(const bf16x8*)&Qg[(size_t)q * HD + kk * 16 + hi * 8];

  f32x16 o0 = {}, o1 = {};
  float mrun = -1e30f;
  float lrun = 0.f;

  const int sr = tid >> 3;
  const int scz = ((tid & 7) ^ (sr & 7)) * 8;
  const u16* kp = Kg + sr * 64 + scz;
  const u16* vp = Vg + (size_t)sr * S_LEN + scz;

  const int ntblk = (q0 + 128) >> 6;  // always even
  const int qmax = qw + 31;

  // prologue: stage tile 0 into buf 0; drain loads + bias ds_writes, 1 barrier
  g2l16(kp, Ks[0] + tid * 8);
  g2l16(kp + 32 * 64, Ks[0] + tid * 8 + 2048);
  g2l16(vp, Vs[0] + tid * 8);
  g2l16(vp + 32 * S_LEN, Vs[0] + tid * 8 + 2048);
  kp += 4096;
  vp += 64;
  phase_end();

  const float bias31 = bias_s[255];

  int t = 0;
  while (t < ntblk) {
    tile_body<0>(t, ntblk, qmax, qw, q, hi, la, tid, kp, vp, Ks, Vs, qfrag, bias_s, bias31,
                 mrun, lrun, o0, o1);
    ++t;
    tile_body<1>(t, ntblk, qmax, qw, q, hi, la, tid, kp, vp, Ks, Vs, qfrag, bias_s, bias31,
                 mrun, lrun, o0, o1);
    ++t;
  }

  const float inv = 1.0f / lrun;
  u16* Og = O + ((size_t)(b * S_LEN + q)) * EMB + h * HD;
#pragma unroll
  for (int d2 = 0; d2 < 2; d2++) {
    const f32x16& oa = d2 ? o1 : o0;
#pragma unroll
    for (int g = 0; g < 4; g++) {
      ushort4 ov;
      ov.x = f2bf(oa[g * 4 + 0] * inv);
      ov.y = f2bf(oa[g * 4 + 1] * inv);
      ov.z = f2bf(oa[g * 4 + 2] * inv);
      ov.w = f2bf(oa[g * 4 + 3] * inv);
      *(ushort4*)&Og[d2 * 32 + g * 8 + hi * 4] = ov;
    }
  }
}

// ---------------- host ----------------

extern "C" void kernel_launch(void* const* d_in, const int* in_sizes, int n_in, void* d_out,
                              int out_size, void* d_ws, size_t ws_size, hipStream_t stream) {
  (void)in_sizes; (void)n_in; (void)out_size; (void)ws_size;
  const float* inq = (const float*)d_in[0];
  const float* inkv = (const float*)d_in[1];
  // d_in[2] = mask (causal tril, applied analytically)
  const float* Wq = (const float*)d_in[3];
  const float* Wk = (const float*)d_in[4];
  const float* Wv = (const float*)d_in[5];
  const float* Wo = (const float*)d_in[6];
  const float* rel = (const float*)d_in[7];
  float* out = (float*)d_out;

  char* ws = (char*)d_ws;
  size_t off = 0;
  auto alloc = [&](size_t bytes) {
    void* p = ws + off;
    off += (bytes + 255) & ~(size_t)255;
    return p;
  };
  u16* Aq = (u16*)alloc(16777216);     // inputs_q bf16 [8192][1024]
  u16* Akv = (u16*)alloc(16777216);    // inputs_kv bf16
  u16* Wqkvt = (u16*)alloc(6291456);   // [Wq^T;Wk^T;Wv^T] bf16 [3072][1024]
  u16* Wot = (u16*)alloc(2097152);     // Wo^T bf16
  u16* QKV = (u16*)alloc(50331648);    // Qb | Kb | Vtb (each 8M u16)
  u16* Ob = (u16*)alloc(16777216);     // attn out bf16 [b][s][h*64+d]
  float* btbl = (float*)alloc(16384);  // bias table [16][256] f32

  u16* Qb = QKV;
  u16* Kb = QKV + 8388608;
  u16* Vtb = QKV + 16777216;

  cvt_bf16_2<<<16384, 256, 0, stream>>>(inq, inkv, Aq, Akv);
  transcvt4<<<dim3(32, 32, 4), 256, 0, stream>>>(Wq, Wk, Wv, Wo, Wqkvt, Wot);
  build_bias<<<16, 256, 0, stream>>>(rel, btbl);

  gemm_qkv<<<1536, 256, 0, stream>>>(Aq, Akv, Wqkvt, QKV, QSCALE);
  attn_kernel<<<dim3(64, 16), 256, 0, stream>>>(Qb, Kb, Vtb, btbl, Ob);
  gemm_out<<<512, 256, 0, stream>>>(Ob, Wot, out);
}

// Round 15
// 195.536 us; speedup vs baseline: 1.0685x; 1.0685x over previous
//
#include <hip/hip_runtime.h>

typedef unsigned short u16;
typedef unsigned int u32;
typedef __bf16 bf16x8 __attribute__((ext_vector_type(8)));
typedef float f32x2 __attribute__((ext_vector_type(2)));
typedef float f32x4 __attribute__((ext_vector_type(4)));
typedef float f32x16 __attribute__((ext_vector_type(16)));

#define S_LEN 2048
#define EMB 1024
#define NH 16
#define HD 64
#define LOG2E 1.44269504088896f
#define QSCALE (0.125f * LOG2E)
#define THRL 11.5415603f /* 8 * LOG2E */
#define FB(r) ((((r) ^ ((r) >> 2))) & 3)
#define MEMB asm volatile("" ::: "memory")

__device__ __forceinline__ u16 f2bf(float f) {
  union { float f; unsigned u; } v; v.f = f;
  unsigned r = (v.u + 0x7fffu + ((v.u >> 16) & 1u)) >> 16;
  return (u16)r;
}

__device__ __forceinline__ u32 packbf(float a, float b) {
  union { __bf16 h[2]; u32 u; } x;
  x.h[0] = (__bf16)a; x.h[1] = (__bf16)b;
  return x.u;
}

__device__ __forceinline__ void g2l16(const void* g, void* l) {
  __builtin_amdgcn_global_load_lds(
      (const unsigned int __attribute__((address_space(1)))*)g,
      (unsigned int __attribute__((address_space(3)))*)l, 16, 0, 0);
}

__device__ __forceinline__ float permswap_max(float a) {
  auto r = __builtin_amdgcn_permlane32_swap(__float_as_int(a), __float_as_int(a), false, false);
  return fmaxf(__int_as_float(r[0]), __int_as_float(r[1]));
}
__device__ __forceinline__ float permswap_add(float a) {
  auto r = __builtin_amdgcn_permlane32_swap(__float_as_int(a), __float_as_int(a), false, false);
  return __int_as_float(r[0]) + __int_as_float(r[1]);
}

__device__ __forceinline__ void phase_end() {
  asm volatile("s_waitcnt lgkmcnt(0)" ::: "memory");
  asm volatile("s_waitcnt vmcnt(0)" ::: "memory");
  __builtin_amdgcn_s_barrier();
  MEMB;
}

// ---------------- conversion kernels ----------------

__global__ void cvt_bf16_2(const float* __restrict__ aq, const float* __restrict__ akv,
                           u16* __restrict__ dq, u16* __restrict__ dkv) {
  int i = blockIdx.x * blockDim.x + threadIdx.x;
  const float4* s;
  ushort4* d;
  int j;
  if (i < 2097152) {
    s = (const float4*)aq; d = (ushort4*)dq; j = i;
  } else {
    s = (const float4*)akv; d = (ushort4*)dkv; j = i - 2097152;
  }
  float4 f = s[j];
  ushort4 o;
  o.x = f2bf(f.x); o.y = f2bf(f.y); o.z = f2bf(f.z); o.w = f2bf(f.w);
  d[j] = o;
}

__global__ void transcvt4(const float* __restrict__ W0, const float* __restrict__ W1,
                          const float* __restrict__ W2, const float* __restrict__ W3,
                          u16* __restrict__ Dqkv, u16* __restrict__ Do) {
  __shared__ float t[32][33];
  const int z = blockIdx.z;
  const float* W = (z == 0) ? W0 : (z == 1) ? W1 : (z == 2) ? W2 : W3;
  u16* Wt = (z < 3) ? (Dqkv + (size_t)z * 1048576) : Do;
  int k0 = blockIdx.x * 32, n0 = blockIdx.y * 32;
  int tx = threadIdx.x & 31, ty = threadIdx.x >> 5;
#pragma unroll
  for (int i = 0; i < 4; i++) t[ty + i * 8][tx] = W[(k0 + ty + i * 8) * 1024 + n0 + tx];
  __syncthreads();
#pragma unroll
  for (int i = 0; i < 4; i++) Wt[(n0 + ty + i * 8) * 1024 + k0 + tx] = f2bf(t[tx][ty + i * 8]);
}

// bias table in log2 units, 256 entries/head (bucket saturates at dist>=113)
__global__ void build_bias(const float* __restrict__ rel, float* __restrict__ tbl) {
  int i = blockIdx.x * 256 + threadIdx.x;  // 0..4095
  int h = i >> 8, dist = i & 255;
  int bk;
  if (dist < 16) {
    bk = dist;
  } else {
    float ls = logf((float)dist * (1.0f / 16.0f)) * (1.0f / logf(8.0f));
    bk = 16 + (int)(ls * 16.0f);
    if (bk > 31) bk = 31;
  }
  tbl[i] = rel[h * 32 + bk] * LOG2E;
}

// ---------------- fused QKV GEMM: 128x128, BK=32, 3-buffer counted-vmcnt ----------------
// SWAPPED MFMA (acc = C^T): reg-quad -> 4 consecutive n, lane -> m.

__global__ __launch_bounds__(256, 3) void gemm_qkv(const u16* __restrict__ Aq,
                                                   const u16* __restrict__ Akv,
                                                   const u16* __restrict__ Wt,
                                                   u16* __restrict__ QKV, float qscale) {
  constexpr int K = EMB;
  __shared__ u16 As[3][128 * 32];
  __shared__ u16 Bs[3][128 * 32];

  const int bid = blockIdx.x;
  const int xcd = bid & 7, idx = bid >> 3;  // 192 blocks per XCD chunk
  const int mt = xcd * 8 + (idx & 7);       // 64 m-tiles
  const int nt = idx >> 3;                  // 24 n-tiles
  const int m0 = mt * 128;
  const int n0 = nt * 128;
  const int mat = n0 >> 10;  // 0=Q 1=K 2=V (block-uniform)
  const u16* A = (mat == 0) ? Aq : Akv;

  const int tid = threadIdx.x;
  const int lane = tid & 63;
  const int wid = tid >> 6;
  const int wm = (wid >> 1) * 64;
  const int wn = (wid & 1) * 64;
  const int la = lane & 15;
  const int lg = lane >> 4;

  const int r0 = tid >> 2;
  const int c0 = ((tid & 3) ^ FB(r0)) * 8;
  const u16* gA = A + (size_t)(m0 + r0) * K + c0;
  const u16* gB = Wt + (size_t)(n0 + r0) * K + c0;

  auto stage = [&](int b) {
    u16* lA = As[b] + tid * 8;
    u16* lB = Bs[b] + tid * 8;
    g2l16(gA, lA);
    g2l16(gA + 64 * K, lA + 2048);
    g2l16(gB, lB);
    g2l16(gB + 64 * K, lB + 2048);
    gA += 32;
    gB += 32;
  };

  f32x4 acc[4][4] = {};

  stage(0);
  stage(1);
  asm volatile("s_waitcnt vmcnt(4)" ::: "memory");
  __builtin_amdgcn_s_barrier();
  MEMB;

  int cur = 0;
  for (int t = 0; t < 32; ++t) {
    if (t < 30) {
      int nxt = cur + 2;
      if (nxt > 2) nxt -= 3;
      stage(nxt);
    }

    bf16x8 af[4], bb[4];
#pragma unroll
    for (int mf = 0; mf < 4; mf++) {
      int row = wm + mf * 16 + la;
      af[mf] = *(const bf16x8*)&As[cur][row * 32 + ((lg ^ FB(row)) << 3)];
    }
#pragma unroll
    for (int nf = 0; nf < 4; nf++) {
      int row = wn + nf * 16 + la;
      bb[nf] = *(const bf16x8*)&Bs[cur][row * 32 + ((lg ^ FB(row)) << 3)];
    }
    __builtin_amdgcn_s_setprio(1);
#pragma unroll
    for (int mf = 0; mf < 4; mf++)
#pragma unroll
      for (int nf = 0; nf < 4; nf++)
        acc[mf][nf] =
            __builtin_amdgcn_mfma_f32_16x16x32_bf16(bb[nf], af[mf], acc[mf][nf], 0, 0, 0);
    __builtin_amdgcn_s_setprio(0);

    asm volatile("s_waitcnt lgkmcnt(0)" ::: "memory");
    if (t < 30) asm volatile("s_waitcnt vmcnt(4)" ::: "memory");
    else        asm volatile("s_waitcnt vmcnt(0)" ::: "memory");
    __builtin_amdgcn_s_barrier();
    MEMB;

    cur = (cur == 2) ? 0 : cur + 1;
  }

  const float sc = (mat == 0) ? qscale : 1.0f;
  const size_t base = (size_t)mat << 23;
  if (mat < 2) {
#pragma unroll
    for (int mf = 0; mf < 4; mf++) {
      const int m = m0 + wm + mf * 16 + la;
      const int b = m >> 11, s = m & 2047;
#pragma unroll
      for (int nf = 0; nf < 4; nf++) {
        const int n = n0 + wn + nf * 16 + lg * 4;
        const int hh = (n >> 6) & 15, d0 = n & 63;
        ushort4 ov;
        ov.x = f2bf(acc[mf][nf][0] * sc);
        ov.y = f2bf(acc[mf][nf][1] * sc);
        ov.z = f2bf(acc[mf][nf][2] * sc);
        ov.w = f2bf(acc[mf][nf][3] * sc);
        *(ushort4*)&QKV[base + (((size_t)(b * 16 + hh) * 2048 + s) << 6) + d0] = ov;
      }
    }
  } else {
#pragma unroll
    for (int mf = 0; mf < 4; mf++) {
      const int m = m0 + wm + mf * 16 + la;
      const int b = m >> 11, s = m & 2047;
#pragma unroll
      for (int nf = 0; nf < 4; nf++)
#pragma unroll
        for (int r = 0; r < 4; r++) {
          const int n = n0 + wn + nf * 16 + lg * 4 + r;
          const int hh = (n >> 6) & 15, d = n & 63;
          QKV[base + (((size_t)(b * 16 + hh) * 64 + d) << 11) + s] = f2bf(acc[mf][nf][r]);
        }
    }
  }
}

// ---------------- output GEMM: out[M,1024] f32 = Ob * Wot^T ----------------

__global__ __launch_bounds__(256, 3) void gemm_out(const u16* __restrict__ A,
                                                   const u16* __restrict__ Bt,
                                                   float* __restrict__ C) {
  constexpr int K = EMB;
  __shared__ u16 As[3][128 * 32];
  __shared__ u16 Bs[3][128 * 32];
  const int bid = blockIdx.x;
  const int xcd = bid & 7, idx = bid >> 3;
  const int mt = xcd * 8 + (idx & 7);
  const int nt = idx >> 3;
  const int m0 = mt * 128;
  const int n0 = nt * 128;
  const int tid = threadIdx.x;
  const int lane = tid & 63;
  const int wid = tid >> 6;
  const int wm = (wid >> 1) * 64;
  const int wn = (wid & 1) * 64;
  const int la = lane & 15;
  const int lg = lane >> 4;

  const int r0 = tid >> 2;
  const int c0 = ((tid & 3) ^ FB(r0)) * 8;
  const u16* gA = A + (size_t)(m0 + r0) * K + c0;
  const u16* gB = Bt + (size_t)(n0 + r0) * K + c0;

  auto stage = [&](int b) {
    u16* lA = As[b] + tid * 8;
    u16* lB = Bs[b] + tid * 8;
    g2l16(gA, lA);
    g2l16(gA + 64 * K, lA + 2048);
    g2l16(gB, lB);
    g2l16(gB + 64 * K, lB + 2048);
    gA += 32;
    gB += 32;
  };

  f32x4 acc[4][4] = {};

  stage(0);
  stage(1);
  asm volatile("s_waitcnt vmcnt(4)" ::: "memory");
  __builtin_amdgcn_s_barrier();
  MEMB;

  int cur = 0;
  for (int t = 0; t < 32; ++t) {
    if (t < 30) {
      int nxt = cur + 2;
      if (nxt > 2) nxt -= 3;
      stage(nxt);
    }

    bf16x8 af[4], bb[4];
#pragma unroll
    for (int mf = 0; mf < 4; mf++) {
      int row = wm + mf * 16 + la;
      af[mf] = *(const bf16x8*)&As[cur][row * 32 + ((lg ^ FB(row)) << 3)];
    }
#pragma unroll
    for (int nf = 0; nf < 4; nf++) {
      int row = wn + nf * 16 + la;
      bb[nf] = *(const bf16x8*)&Bs[cur][row * 32 + ((lg ^ FB(row)) << 3)];
    }
    __builtin_amdgcn_s_setprio(1);
#pragma unroll
    for (int mf = 0; mf < 4; mf++)
#pragma unroll
      for (int nf = 0; nf < 4; nf++)
        acc[mf][nf] =
            __builtin_amdgcn_mfma_f32_16x16x32_bf16(bb[nf], af[mf], acc[mf][nf], 0, 0, 0);
    __builtin_amdgcn_s_setprio(0);

    asm volatile("s_waitcnt lgkmcnt(0)" ::: "memory");
    if (t < 30) asm volatile("s_waitcnt vmcnt(4)" ::: "memory");
    else        asm volatile("s_waitcnt vmcnt(0)" ::: "memory");
    __builtin_amdgcn_s_barrier();
    MEMB;

    cur = (cur == 2) ? 0 : cur + 1;
  }

#pragma unroll
  for (int mf = 0; mf < 4; mf++) {
    const int m = m0 + wm + mf * 16 + la;
#pragma unroll
    for (int nf = 0; nf < 4; nf++) {
      const int n = n0 + wn + nf * 16 + lg * 4;
      float4 ov;
      ov.x = acc[mf][nf][0];
      ov.y = acc[mf][nf][1];
      ov.z = acc[mf][nf][2];
      ov.w = acc[mf][nf][3];
      *(float4*)&C[(size_t)m * 1024 + n] = ov;
    }
  }
}

// ---------------- flash attention, 2-phase dbuf; LDS 33 KB -> 4 blocks/CU ----------------
// grid (64 bh, 16 qt); launch_bounds (256,3) keeps regalloc at 72 VGPR (no spill).

__device__ __forceinline__ void softmax_repack(const f32x16* sacc, int kv0, int qw, int q, int hi,
                                               const float* bias_s, float bias31, float& mrun,
                                               float& lrun, f32x16& o0, f32x16& o1,
                                               u32 (&paw)[4][4]) {
  f32x2 pf[16];  // pf[j] = scores (r=2j', 2j'+1) of nf=j>>3, j'=j&7  (log2 units)
  float adde = 0.f;
  if (kv0 + 176 <= qw) {  // FAR: bucket 31 everywhere, bias folded into exp constant
#pragma unroll
    for (int j = 0; j < 16; j++) {
      const int nf = j >> 3, r = (j & 7) * 2;
      pf[j] = (f32x2){sacc[nf][r], sacc[nf][r + 1]};
    }
    adde = bias31;
  } else {
    const int qb2 = q - kv0 - 4 * hi;
    const float* bp = bias_s + (qb2 - 59);  // bp[59-Cn] = bias_s[qb2-Cn], Cn<=59
    if (kv0 + 63 <= qw) {  // NEAR-full: per-score bias, no mask
#pragma unroll
      for (int j = 0; j < 16; j++) {
        const int nf = j >> 3, r = (j & 7) * 2;
        const int Cn = nf * 32 + (r & 3) + ((r >> 2) << 3);
        f32x2 bv = {bp[59 - Cn], bp[58 - Cn]};
        pf[j] = (f32x2){sacc[nf][r], sacc[nf][r + 1]} + bv;
      }
    } else {  // DIAG: mask (OOB-LDS bias reads are masked out)
#pragma unroll
      for (int j = 0; j < 16; j++) {
        const int nf = j >> 3, r = (j & 7) * 2;
        const int Cn = nf * 32 + (r & 3) + ((r >> 2) << 3);
        pf[j].x = (Cn <= qb2) ? (sacc[nf][r] + bp[59 - Cn]) : -1e30f;
        pf[j].y = (Cn + 1 <= qb2) ? (sacc[nf][r + 1] + bp[58 - Cn]) : -1e30f;
      }
    }
  }

  // tile max: pk_max tree
  f32x2 t8[8];
#pragma unroll
  for (int i = 0; i < 8; i++) t8[i] = __builtin_elementwise_max(pf[i], pf[i + 8]);
#pragma unroll
  for (int i = 0; i < 4; i++) t8[i] = __builtin_elementwise_max(t8[i], t8[i + 4]);
  f32x2 m2 = __builtin_elementwise_max(__builtin_elementwise_max(t8[0], t8[1]),
                                       __builtin_elementwise_max(t8[2], t8[3]));
  float mt = fmaxf(m2.x, m2.y) + adde;
  mt = permswap_max(mt);

  // defer-max (T13)
  if (__any(mt > mrun + THRL)) {
    float mn = fmaxf(mrun, mt);
    float s = exp2f(mrun - mn);
    mrun = mn;
    lrun *= s;
    o0 *= s;
    o1 *= s;
  }
  const f32x2 ec2 = {adde - mrun, adde - mrun};

  // exp + sum
  f32x2 s8[8];
#pragma unroll
  for (int j = 0; j < 16; j++) {
    f32x2 a = pf[j] + ec2;
    f32x2 p = {exp2f(a.x), exp2f(a.y)};
    pf[j] = p;
    if (j < 8) s8[j] = p;
    else s8[j - 8] += p;
  }
#pragma unroll
  for (int i = 0; i < 4; i++) s8[i] += s8[i + 4];
  f32x2 s2 = (s8[0] + s8[1]) + (s8[2] + s8[3]);
  lrun += permswap_add(s2.x + s2.y);

  // repack P^T into PV B-fragments (pair-pack + permlane32_swap)
#pragma unroll
  for (int ks = 0; ks < 4; ks++) {
    const int j0b = (ks >> 1) * 8 + (ks & 1) * 4;
#pragma unroll
    for (int half = 0; half < 2; half++) {
      u32 Y0 = packbf(pf[j0b + half].x, pf[j0b + half].y);
      u32 Y1 = packbf(pf[j0b + 2 + half].x, pf[j0b + 2 + half].y);
      auto r = __builtin_amdgcn_permlane32_swap((int)Y0, (int)Y1, false, false);
      paw[ks][half] = (u32)r[0];
      paw[ks][2 + half] = (u32)r[1];
    }
  }
}

template <int CUR>
__device__ __forceinline__ void tile_body(int t, int ntblk, int qmax, int qw, int q, int hi,
                                          int la, int tid, const u16*& kp, const u16*& vp,
                                          u16 (*Ks)[64 * 64], u16 (*Vs)[64 * 64],
                                          const bf16x8 (&qfrag)[4], const float* bias_s,
                                          float bias31, float& mrun, float& lrun, f32x16& o0,
                                          f32x16& o1) {
  if (t + 1 < ntblk) {  // issue next-tile stage early; drains at end of this iter
    u16* lK = Ks[CUR ^ 1] + tid * 8;
    u16* lV = Vs[CUR ^ 1] + tid * 8;
    g2l16(kp, lK);
    g2l16(kp + 32 * 64, lK + 2048);
    g2l16(vp, lV);
    g2l16(vp + 32 * S_LEN, lV + 2048);
    kp += 4096;
    vp += 64;
  }

  const int kv0 = t << 6;
  if (kv0 <= qmax) {
    f32x16 sacc[2] = {};
    __builtin_amdgcn_s_setprio(1);
#pragma unroll
    for (int kk = 0; kk < 4; kk++)
#pragma unroll
      for (int nf = 0; nf < 2; nf++) {
        int row = nf * 32 + la;
        bf16x8 kf = *(const bf16x8*)&Ks[CUR][row * 64 + (((kk * 2 + hi) ^ (row & 7)) << 3)];
        sacc[nf] = __builtin_amdgcn_mfma_f32_32x32x16_bf16(kf, qfrag[kk], sacc[nf], 0, 0, 0);
      }
    __builtin_amdgcn_s_setprio(0);

    u32 paw[4][4];
    softmax_repack(sacc, kv0, qw, q, hi, bias_s, bias31, mrun, lrun, o0, o1, paw);

    __builtin_amdgcn_s_setprio(1);
#pragma unroll
    for (int d2 = 0; d2 < 2; d2++) {
      f32x16& oa = d2 ? o1 : o0;
#pragma unroll
      for (int ks = 0; ks < 4; ks++) {
        int row = d2 * 32 + la;
        bf16x8 vf = *(const bf16x8*)&Vs[CUR][row * 64 + (((ks * 2 + hi) ^ (row & 7)) << 3)];
        union { u32 w[4]; bf16x8 v; } pu;
        pu.w[0] = paw[ks][0]; pu.w[1] = paw[ks][1];
        pu.w[2] = paw[ks][2]; pu.w[3] = paw[ks][3];
        oa = __builtin_amdgcn_mfma_f32_32x32x16_bf16(vf, pu.v, oa, 0, 0, 0);
      }
    }
    __builtin_amdgcn_s_setprio(0);
  }

  phase_end();
}

__global__ __launch_bounds__(256, 3) void attn_kernel(const u16* __restrict__ Qb,
                                                      const u16* __restrict__ Kb,
                                                      const u16* __restrict__ Vtb,
                                                      const float* __restrict__ btbl,
                                                      u16* __restrict__ O) {
  __shared__ u16 Ks[2][64 * 64];
  __shared__ u16 Vs[2][64 * 64];
  __shared__ float bias_s[256];

  const int bh = blockIdx.x;
  const int h = bh & (NH - 1);
  const int b = bh >> 4;
  const int qt = 15 - blockIdx.y;  // heavy tiles dispatch first
  const int q0 = qt * 128;
  const int tid = threadIdx.x;
  const int lane = tid & 63;
  const int w = tid >> 6;
  const int la = lane & 31;
  const int hi = lane >> 5;

  if (tid < 64) ((float4*)bias_s)[tid] = ((const float4*)(btbl + h * 256))[tid];

  const u16* Qg = Qb + (size_t)bh * S_LEN * HD;
  const u16* Kg = Kb + (size_t)bh * S_LEN * HD;
  const u16* Vg = Vtb + (size_t)bh * HD * S_LEN;

  const int qw = q0 + w * 32;
  const int q = qw + la;

  bf16x8 qfrag[4];
#pragma unroll
  for (int kk = 0; kk < 4; kk++)
    qfrag[kk] = *(const bf16x8*)&Qg[(size_t)q * HD + kk * 16 + hi * 8];

  f32x16 o0 = {}, o1 = {};
  float mrun = -1e30f;
  float lrun = 0.f;

  const int sr = tid >> 3;
  const int scz = ((tid & 7) ^ (sr & 7)) * 8;
  const u16* kp = Kg + sr * 64 + scz;
  const u16* vp = Vg + (size_t)sr * S_LEN + scz;

  const int ntblk = (q0 + 128) >> 6;  // always even
  const int qmax = qw + 31;

  // prologue: stage tile 0 into buf 0; drain loads + bias ds_writes, 1 barrier
  g2l16(kp, Ks[0] + tid * 8);
  g2l16(kp + 32 * 64, Ks[0] + tid * 8 + 2048);
  g2l16(vp, Vs[0] + tid * 8);
  g2l16(vp + 32 * S_LEN, Vs[0] + tid * 8 + 2048);
  kp += 4096;
  vp += 64;
  phase_end();

  const float bias31 = bias_s[255];

  int t = 0;
  while (t < ntblk) {
    tile_body<0>(t, ntblk, qmax, qw, q, hi, la, tid, kp, vp, Ks, Vs, qfrag, bias_s, bias31,
                 mrun, lrun, o0, o1);
    ++t;
    tile_body<1>(t, ntblk, qmax, qw, q, hi, la, tid, kp, vp, Ks, Vs, qfrag, bias_s, bias31,
                 mrun, lrun, o0, o1);
    ++t;
  }

  const float inv = 1.0f / lrun;
  u16* Og = O + ((size_t)(b * S_LEN + q)) * EMB + h * HD;
#pragma unroll
  for (int d2 = 0; d2 < 2; d2++) {
    const f32x16& oa = d2 ? o1 : o0;
#pragma unroll
    for (int g = 0; g < 4; g++) {
      ushort4 ov;
      ov.x = f2bf(oa[g * 4 + 0] * inv);
      ov.y = f2bf(oa[g * 4 + 1] * inv);
      ov.z = f2bf(oa[g * 4 + 2] * inv);
      ov.w = f2bf(oa[g * 4 + 3] * inv);
      *(ushort4*)&Og[d2 * 32 + g * 8 + hi * 4] = ov;
    }
  }
}

// ---------------- host ----------------

extern "C" void kernel_launch(void* const* d_in, const int* in_sizes, int n_in, void* d_out,
                              int out_size, void* d_ws, size_t ws_size, hipStream_t stream) {
  (void)in_sizes; (void)n_in; (void)out_size; (void)ws_size;
  const float* inq = (const float*)d_in[0];
  const float* inkv = (const float*)d_in[1];
  // d_in[2] = mask (causal tril, applied analytically)
  const float* Wq = (const float*)d_in[3];
  const float* Wk = (const float*)d_in[4];
  const float* Wv = (const float*)d_in[5];
  const float* Wo = (const float*)d_in[6];
  const float* rel = (const float*)d_in[7];
  float* out = (float*)d_out;

  char* ws = (char*)d_ws;
  size_t off = 0;
  auto alloc = [&](size_t bytes) {
    void* p = ws + off;
    off += (bytes + 255) & ~(size_t)255;
    return p;
  };
  u16* Aq = (u16*)alloc(16777216);     // inputs_q bf16 [8192][1024]
  u16* Akv = (u16*)alloc(16777216);    // inputs_kv bf16
  u16* Wqkvt = (u16*)alloc(6291456);   // [Wq^T;Wk^T;Wv^T] bf16 [3072][1024]
  u16* Wot = (u16*)alloc(2097152);     // Wo^T bf16
  u16* QKV = (u16*)alloc(50331648);    // Qb | Kb | Vtb (each 8M u16)
  u16* Ob = (u16*)alloc(16777216);     // attn out bf16 [b][s][h*64+d]
  float* btbl = (float*)alloc(16384);  // bias table [16][256] f32

  u16* Qb = QKV;
  u16* Kb = QKV + 8388608;
  u16* Vtb = QKV + 16777216;

  cvt_bf16_2<<<16384, 256, 0, stream>>>(inq, inkv, Aq, Akv);
  transcvt4<<<dim3(32, 32, 4), 256, 0, stream>>>(Wq, Wk, Wv, Wo, Wqkvt, Wot);
  build_bias<<<16, 256, 0, stream>>>(rel, btbl);

  gemm_qkv<<<1536, 256, 0, stream>>>(Aq, Akv, Wqkvt, QKV, QSCALE);
  attn_kernel<<<dim3(64, 16), 256, 0, stream>>>(Qb, Kb, Vtb, btbl, Ob);
  gemm_out<<<512, 256, 0, stream>>>(Ob, Wot, out);
}